// Round 1
// baseline (520.941 us; speedup 1.0000x reference)
//
#include <hip/hip_runtime.h>

typedef unsigned short u16;
typedef unsigned int   u32;
typedef short  short8   __attribute__((ext_vector_type(8)));
typedef float  floatx4  __attribute__((ext_vector_type(4)));
typedef u32    uintx4   __attribute__((ext_vector_type(4)));
typedef u16    ushortx2 __attribute__((ext_vector_type(2)));
typedef u16    ushortx4 __attribute__((ext_vector_type(4)));

__device__ __forceinline__ float bf2f(u16 u) {
  union { u32 i; float f; } v; v.i = ((u32)u) << 16; return v.f;
}
__device__ __forceinline__ u16 f2bf(float x) {
  union { float f; u32 i; } v; v.f = x;
  u32 r = v.i + 0x7FFFu + ((v.i >> 16) & 1u);   // round-to-nearest-even
  return (u16)(r >> 16);
}

// ---------------------------------------------------------------------------
// fp32 -> bf16 bulk convert (4 elems/thread)
// ---------------------------------------------------------------------------
__global__ __launch_bounds__(256) void cvt_bf16(const floatx4* __restrict__ in,
                                                ushortx4* __restrict__ out) {
  int i = blockIdx.x * 256 + threadIdx.x;
  floatx4 v = in[i];
  ushortx4 o;
  o.x = f2bf(v.x); o.y = f2bf(v.y); o.z = f2bf(v.z); o.w = f2bf(v.w);
  out[i] = o;
}

// ---------------------------------------------------------------------------
// Batched BT-GEMM: C[m][n] = sum_k A[m][k] * B[n][k]   (A: MxK, B: NxK, bf16)
// 128x128 tile, BK=32, 4 waves of 4x4 16x16x32 MFMAs (guide-verified layout).
// blockIdx.z batches heads via batchA/B/C element strides.
// ---------------------------------------------------------------------------
__global__ __launch_bounds__(256) void gemm_bt(
    const u16* __restrict__ A, const u16* __restrict__ B, void* __restrict__ Cv,
    int M, int N, int K, int lda, int ldb, int ldc,
    long batchA, long batchB, long batchC, int outBF16) {
  A += (long)blockIdx.z * batchA;
  B += (long)blockIdx.z * batchB;
  const long cbase = (long)blockIdx.z * batchC;

  __shared__ __align__(16) u16 As[128][32];
  __shared__ __align__(16) u16 Bs[128][32];

  const int t = threadIdx.x;
  const int lane = t & 63;
  const int wave = t >> 6;
  const int wm = (wave >> 1) << 6;   // wave row offset: 0 / 64
  const int wn = (wave & 1) << 6;    // wave col offset: 0 / 64
  const int quad = lane >> 4;        // k-quad: frag holds k = quad*8 + j
  const int mrow = lane & 15;        // m (A) / n (B) index within 16
  const int m0 = blockIdx.y << 7;
  const int n0 = blockIdx.x << 7;

  floatx4 acc[4][4] = {};

  const int srow = t >> 1;           // staging: 128 rows x 2 half-rows
  const int sseg = (t & 1) << 4;     // 0 or 16 u16 (32B each)

  for (int k0 = 0; k0 < K; k0 += 32) {
    __syncthreads();
    const uintx4* sa = (const uintx4*)(A + (long)(m0 + srow) * lda + k0 + sseg);
    uintx4* da = (uintx4*)&As[srow][sseg];
    da[0] = sa[0]; da[1] = sa[1];
    const uintx4* sb = (const uintx4*)(B + (long)(n0 + srow) * ldb + k0 + sseg);
    uintx4* db = (uintx4*)&Bs[srow][sseg];
    db[0] = sb[0]; db[1] = sb[1];
    __syncthreads();

    short8 af[4], bfr[4];
#pragma unroll
    for (int i = 0; i < 4; i++)
      af[i] = *(const short8*)&As[wm + (i << 4) + mrow][quad << 3];
#pragma unroll
    for (int j = 0; j < 4; j++)
      bfr[j] = *(const short8*)&Bs[wn + (j << 4) + mrow][quad << 3];
#pragma unroll
    for (int i = 0; i < 4; i++)
#pragma unroll
      for (int j = 0; j < 4; j++)
        acc[i][j] = __builtin_amdgcn_mfma_f32_16x16x32_bf16(af[i], bfr[j], acc[i][j], 0, 0, 0);
  }

  // epilogue: C/D layout col = lane&15, row = quad*4 + reg  [measured m89/m91]
#pragma unroll
  for (int i = 0; i < 4; i++) {
    int row0 = m0 + wm + (i << 4) + (quad << 2);
#pragma unroll
    for (int j = 0; j < 4; j++) {
      int col = n0 + wn + (j << 4) + mrow;
#pragma unroll
      for (int r = 0; r < 4; r++) {
        long idx = cbase + (long)(row0 + r) * ldc + col;
        float val = acc[i][j][r];
        if (outBF16) ((u16*)Cv)[idx] = f2bf(val);
        else         ((float*)Cv)[idx] = val;
      }
    }
  }
}

// ---------------------------------------------------------------------------
// RoPE (interleaved pairs) applied in-place to bf16 q and k.
// q additionally scaled by 1/sqrt(DH) so scores GEMM needs no scale.
// grid: (S*H*HALF/256, 2); y==0 -> q, y==1 -> k
// ---------------------------------------------------------------------------
__global__ __launch_bounds__(256) void rope_qk(u16* __restrict__ qb, u16* __restrict__ kb,
                                               const float* __restrict__ cs,
                                               const float* __restrict__ sn) {
  int idx = blockIdx.x * 256 + threadIdx.x;   // [0, 2048*16*64)
  int p = idx & 63;
  int h = (idx >> 6) & 15;
  int s = idx >> 10;
  float c  = cs[(s << 6) | p];
  float si = sn[(s << 6) | p];
  u16* base;
  float scale;
  if (blockIdx.y == 0) { base = qb; scale = 0.08838834764831845f; }  // 1/sqrt(128)
  else                 { base = kb; scale = 1.0f; }
  size_t off = ((size_t)s << 11) + ((size_t)h << 7) + ((size_t)p << 1);
  ushortx2 eo = *(ushortx2*)(base + off);
  float e = bf2f(eo.x), o = bf2f(eo.y);
  ushortx2 r;
  r.x = f2bf((e * c - o * si) * scale);
  r.y = f2bf((e * si + o * c) * scale);
  *(ushortx2*)(base + off) = r;
}

// ---------------------------------------------------------------------------
// Causal softmax over bf16 score rows, in place. Wave per row (4 rows/block).
// Masked cols (k > q) written as exact 0 (== ref's exp(-1e9) underflow).
// ---------------------------------------------------------------------------
__global__ __launch_bounds__(256) void softmax_causal(u16* __restrict__ sc) {
  int wid = (blockIdx.x << 2) | ((int)threadIdx.x >> 6);
  int lane = threadIdx.x & 63;
  int q  = wid & 2047;
  int hl = wid >> 11;
  u16* row = sc + ((size_t)hl * 2048 + q) * 2048;
  int n = q + 1;
  float vals[32];
  float m = -1e30f;
#pragma unroll
  for (int u = 0; u < 32; u++) {
    int c = lane + (u << 6);
    float v = (c < n) ? bf2f(row[c]) : -1e30f;
    vals[u] = v;
    m = fmaxf(m, v);
  }
#pragma unroll
  for (int off = 1; off < 64; off <<= 1) m = fmaxf(m, __shfl_xor(m, off));
  float sum = 0.f;
#pragma unroll
  for (int u = 0; u < 32; u++) {
    int c = lane + (u << 6);
    float p = (c < n) ? __expf(vals[u] - m) : 0.f;
    vals[u] = p;
    sum += p;
  }
#pragma unroll
  for (int off = 1; off < 64; off <<= 1) sum += __shfl_xor(sum, off);
  float rinv = 1.f / sum;
#pragma unroll
  for (int u = 0; u < 32; u++) {
    int c = lane + (u << 6);
    row[c] = f2bf(vals[u] * rinv);
  }
}

// ---------------------------------------------------------------------------
// Orchestration. All contractions are BT-GEMMs:
//   q  = BT(x, wq)        k = BT(x, wk)        vT = BT(wv, x)
//   S_h = BT(q_h, k_h)    AT_h = BT(vT_h, P_h)
//   out = BT(AT, wo)   (the reference's transpose(0,1,3,2).reshape makes the
//                       final GEMM contract over seq with AT[(h*128+d)][q])
// ---------------------------------------------------------------------------
extern "C" void kernel_launch(void* const* d_in, const int* in_sizes, int n_in,
                              void* d_out, int out_size, void* d_ws, size_t ws_size,
                              hipStream_t stream) {
  const float* x  = (const float*)d_in[0];
  const float* fc = (const float*)d_in[1];
  const float* fs = (const float*)d_in[2];
  // d_in[3] mask: causal triu(-1e9) — implemented analytically
  const float* wq = (const float*)d_in[4];
  const float* wk = (const float*)d_in[5];
  const float* wv = (const float*)d_in[6];
  const float* wo = (const float*)d_in[7];
  // d_in[8] start_pos == 0: unused
  float* out = (float*)d_out;

  char* ws = (char*)d_ws;
  const size_t MB = 1024 * 1024;
  u16* XB  = (u16*)(ws + 0 * MB);    // bf16 x           (8 MB)
  u16* WQb = (u16*)(ws + 8 * MB);
  u16* WKb = (u16*)(ws + 16 * MB);
  u16* WVb = (u16*)(ws + 24 * MB);
  u16* WOb = (u16*)(ws + 32 * MB);
  u16* QB  = (u16*)(ws + 40 * MB);   // q[s][h*128+d]
  u16* KB  = (u16*)(ws + 48 * MB);   // k[s][h*128+d]
  u16* VT  = (u16*)(ws + 56 * MB);   // vT[h*128+d][s]
  u16* AT  = (u16*)(ws + 64 * MB);   // attn-out transposed [(h*128+d)][q]
  u16* SC  = (u16*)(ws + 72 * MB);   // scores, 8 MB per in-flight head

  // heads per pass, adapted to workspace (min requirement: 80 MB)
  int hpp = 16;
  while (hpp > 1 && 72 * MB + (size_t)hpp * 8 * MB > ws_size) hpp >>= 1;

  dim3 blk(256);
  cvt_bf16<<<4096, blk, 0, stream>>>((const floatx4*)x,  (ushortx4*)XB);
  cvt_bf16<<<4096, blk, 0, stream>>>((const floatx4*)wq, (ushortx4*)WQb);
  cvt_bf16<<<4096, blk, 0, stream>>>((const floatx4*)wk, (ushortx4*)WKb);
  cvt_bf16<<<4096, blk, 0, stream>>>((const floatx4*)wv, (ushortx4*)WVb);
  cvt_bf16<<<4096, blk, 0, stream>>>((const floatx4*)wo, (ushortx4*)WOb);

  // projections (M=N=K=2048)
  gemm_bt<<<dim3(16, 16, 1), blk, 0, stream>>>(XB,  WQb, QB, 2048, 2048, 2048,
                                               2048, 2048, 2048, 0, 0, 0, 1);
  gemm_bt<<<dim3(16, 16, 1), blk, 0, stream>>>(XB,  WKb, KB, 2048, 2048, 2048,
                                               2048, 2048, 2048, 0, 0, 0, 1);
  gemm_bt<<<dim3(16, 16, 1), blk, 0, stream>>>(WVb, XB,  VT, 2048, 2048, 2048,
                                               2048, 2048, 2048, 0, 0, 0, 1);

  rope_qk<<<dim3(8192, 2), blk, 0, stream>>>(QB, KB, fc, fs);

  for (int h0 = 0; h0 < 16; h0 += hpp) {
    // scores: S_h[q][s] = sum_d q[q][h*128+d] * k[s][h*128+d]   (K=128)
    gemm_bt<<<dim3(16, 16, hpp), blk, 0, stream>>>(QB + h0 * 128, KB + h0 * 128, SC,
        2048, 2048, 128, 2048, 2048, 2048, 128, 128, (long)2048 * 2048, 1);
    softmax_causal<<<hpp * 512, blk, 0, stream>>>(SC);
    // PV: AT_h[d][q] = sum_s vT_h[d][s] * P_h[q][s]   (M=128)
    gemm_bt<<<dim3(16, 1, hpp), blk, 0, stream>>>(VT + (size_t)h0 * 128 * 2048, SC,
        AT + (size_t)h0 * 128 * 2048,
        128, 2048, 2048, 2048, 2048, 2048,
        (long)128 * 2048, (long)2048 * 2048, (long)128 * 2048, 1);
  }

  // final: out[r][j] = sum_q AT[r][q] * wo[j][q]   (fp32 output)
  gemm_bt<<<dim3(16, 16, 1), blk, 0, stream>>>(AT, WOb, out, 2048, 2048, 2048,
                                               2048, 2048, 2048, 0, 0, 0, 0);
}

// Round 2
// 479.373 us; speedup vs baseline: 1.0867x; 1.0867x over previous
//
#include <hip/hip_runtime.h>

typedef unsigned short u16;
typedef unsigned int   u32;
typedef short  short8   __attribute__((ext_vector_type(8)));
typedef float  floatx4  __attribute__((ext_vector_type(4)));
typedef u16    ushortx2 __attribute__((ext_vector_type(2)));
typedef u16    ushortx4 __attribute__((ext_vector_type(4)));

__device__ __forceinline__ float bf2f(u16 u) {
  union { u32 i; float f; } v; v.i = ((u32)u) << 16; return v.f;
}
__device__ __forceinline__ u16 f2bf(float x) {
  union { float f; u32 i; } v; v.f = x;
  u32 r = v.i + 0x7FFFu + ((v.i >> 16) & 1u);   // round-to-nearest-even
  return (u16)(r >> 16);
}

// async global->LDS, 16B per lane; LDS dest = wave-uniform base + lane*16
#define GLOAD_LDS16(gptr, lptr)                                                   \
  __builtin_amdgcn_global_load_lds(                                               \
      (const __attribute__((address_space(1))) void*)(gptr),                      \
      (__attribute__((address_space(3))) void*)(lptr), 16, 0, 0)

// ---------------------------------------------------------------------------
// fp32 -> bf16 bulk convert (4 elems/thread)
// ---------------------------------------------------------------------------
__global__ __launch_bounds__(256) void cvt_bf16(const floatx4* __restrict__ in,
                                                ushortx4* __restrict__ out) {
  int i = blockIdx.x * 256 + threadIdx.x;
  floatx4 v = in[i];
  ushortx4 o;
  o.x = f2bf(v.x); o.y = f2bf(v.y); o.z = f2bf(v.z); o.w = f2bf(v.w);
  out[i] = o;
}

// 4 weight matrices in one launch (blockIdx.y selects)
__global__ __launch_bounds__(256) void cvt_bf16_w4(
    const floatx4* __restrict__ a, const floatx4* __restrict__ b,
    const floatx4* __restrict__ c, const floatx4* __restrict__ d,
    ushortx4* __restrict__ oa, ushortx4* __restrict__ ob,
    ushortx4* __restrict__ oc, ushortx4* __restrict__ od) {
  int i = blockIdx.x * 256 + threadIdx.x;
  const floatx4* in; ushortx4* out;
  switch (blockIdx.y) {
    case 0:  in = a; out = oa; break;
    case 1:  in = b; out = ob; break;
    case 2:  in = c; out = oc; break;
    default: in = d; out = od; break;
  }
  floatx4 v = in[i];
  ushortx4 o;
  o.x = f2bf(v.x); o.y = f2bf(v.y); o.z = f2bf(v.z); o.w = f2bf(v.w);
  out[i] = o;
}

// ---------------------------------------------------------------------------
// Batched BT-GEMM: C[m][n] = sum_k A[m][k] * B[n][k]   (A: MxK, B: NxK, bf16)
// 128x128 tile, BK=32, global_load_lds(16B) staging, XOR-swizzled LDS segs
// (seg' = seg ^ ((row>>1)&3)) -> 2-way bank aliasing (free, m136).
// ---------------------------------------------------------------------------
__global__ __launch_bounds__(256) void gemm_bt(
    const u16* __restrict__ A, const u16* __restrict__ B, void* __restrict__ Cv,
    int M, int N, int K, int lda, int ldb, int ldc,
    long batchA, long batchB, long batchC, int outBF16) {
  A += (long)blockIdx.z * batchA;
  B += (long)blockIdx.z * batchB;
  const long cbase = (long)blockIdx.z * batchC;

  __shared__ __align__(16) u16 As[128][32];
  __shared__ __align__(16) u16 Bs[128][32];

  const int t = threadIdx.x;
  const int lane = t & 63;
  const int wave = t >> 6;
  const int wm = (wave >> 1) << 6;   // wave row offset: 0 / 64
  const int wn = (wave & 1) << 6;    // wave col offset: 0 / 64
  const int quad = lane >> 4;        // k-quad: frag holds k = quad*8 + j
  const int mrow = lane & 15;        // m (A) / n (B) index within 16
  const int m0 = blockIdx.y << 7;
  const int n0 = blockIdx.x << 7;

  floatx4 acc[4][4] = {};

  // staging: wave w covers rows [w*32, w*32+32), two 16-row issues per matrix.
  // lane -> row = w*32 + tt*16 + (lane>>2); LDS slot seg' = lane&3.
  // global seg fetched = seg' ^ ((row>>1)&3) = (lane&3) ^ ((lane>>3)&3).
  const int srow = (wave << 5) + (lane >> 2);
  const int sseg = (((lane & 3) ^ ((lane >> 3) & 3)) << 3);   // u16 offset
  const u16* gA = A + (long)(m0 + srow) * lda + sseg;
  const u16* gB = B + (long)(n0 + srow) * ldb + sseg;
  u16* ldsA0 = &As[(wave << 5)][0];
  u16* ldsA1 = &As[(wave << 5) + 16][0];
  u16* ldsB0 = &Bs[(wave << 5)][0];
  u16* ldsB1 = &Bs[(wave << 5) + 16][0];

  // fragment read: seg quad of row (wm/wn + i*16 + mrow) lives at
  // seg' = quad ^ ((mrow>>1)&3)  (wave/i offsets are multiples of 16 -> no-op)
  const int qsw = ((quad ^ ((mrow >> 1) & 3)) << 3);          // u16 offset

  for (int k0 = 0; k0 < K; k0 += 32) {
    __syncthreads();
    GLOAD_LDS16(gA + k0,            ldsA0);
    GLOAD_LDS16(gA + k0 + 16 * lda, ldsA1);
    GLOAD_LDS16(gB + k0,            ldsB0);
    GLOAD_LDS16(gB + k0 + 16 * ldb, ldsB1);
    __syncthreads();

    short8 af[4], bfr[4];
#pragma unroll
    for (int i = 0; i < 4; i++)
      af[i] = *(const short8*)&As[wm + (i << 4) + mrow][qsw];
#pragma unroll
    for (int j = 0; j < 4; j++)
      bfr[j] = *(const short8*)&Bs[wn + (j << 4) + mrow][qsw];
#pragma unroll
    for (int i = 0; i < 4; i++)
#pragma unroll
      for (int j = 0; j < 4; j++)
        acc[i][j] = __builtin_amdgcn_mfma_f32_16x16x32_bf16(af[i], bfr[j], acc[i][j], 0, 0, 0);
  }

  // epilogue: C/D layout col = lane&15, row = quad*4 + reg  [measured m89/m91]
#pragma unroll
  for (int i = 0; i < 4; i++) {
    int row0 = m0 + wm + (i << 4) + (quad << 2);
#pragma unroll
    for (int j = 0; j < 4; j++) {
      int col = n0 + wn + (j << 4) + mrow;
#pragma unroll
      for (int r = 0; r < 4; r++) {
        long idx = cbase + (long)(row0 + r) * ldc + col;
        float val = acc[i][j][r];
        if (outBF16) ((u16*)Cv)[idx] = f2bf(val);
        else         ((float*)Cv)[idx] = val;
      }
    }
  }
}

// ---------------------------------------------------------------------------
// RoPE (interleaved pairs) applied in-place to bf16 q and k.
// q additionally scaled by 1/sqrt(DH) so scores GEMM needs no scale.
// ---------------------------------------------------------------------------
__global__ __launch_bounds__(256) void rope_qk(u16* __restrict__ qb, u16* __restrict__ kb,
                                               const float* __restrict__ cs,
                                               const float* __restrict__ sn) {
  int idx = blockIdx.x * 256 + threadIdx.x;   // [0, 2048*16*64)
  int p = idx & 63;
  int h = (idx >> 6) & 15;
  int s = idx >> 10;
  float c  = cs[(s << 6) | p];
  float si = sn[(s << 6) | p];
  u16* base;
  float scale;
  if (blockIdx.y == 0) { base = qb; scale = 0.08838834764831845f; }  // 1/sqrt(128)
  else                 { base = kb; scale = 1.0f; }
  size_t off = ((size_t)s << 11) + ((size_t)h << 7) + ((size_t)p << 1);
  ushortx2 eo = *(ushortx2*)(base + off);
  float e = bf2f(eo.x), o = bf2f(eo.y);
  ushortx2 r;
  r.x = f2bf((e * c - o * si) * scale);
  r.y = f2bf((e * si + o * c) * scale);
  *(ushortx2*)(base + off) = r;
}

// ---------------------------------------------------------------------------
// Causal softmax over bf16 score rows, in place. Wave per row (4 rows/block).
// Masked cols (k > q) written as exact 0 (== ref's exp(-1e9) underflow).
// ---------------------------------------------------------------------------
__global__ __launch_bounds__(256) void softmax_causal(u16* __restrict__ sc) {
  int wid = (blockIdx.x << 2) | ((int)threadIdx.x >> 6);
  int lane = threadIdx.x & 63;
  int q  = wid & 2047;
  int hl = wid >> 11;
  u16* row = sc + ((size_t)hl * 2048 + q) * 2048;
  int n = q + 1;
  float vals[32];
  float m = -1e30f;
#pragma unroll
  for (int u = 0; u < 32; u++) {
    int c = lane + (u << 6);
    float v = (c < n) ? bf2f(row[c]) : -1e30f;
    vals[u] = v;
    m = fmaxf(m, v);
  }
#pragma unroll
  for (int off = 1; off < 64; off <<= 1) m = fmaxf(m, __shfl_xor(m, off));
  float sum = 0.f;
#pragma unroll
  for (int u = 0; u < 32; u++) {
    int c = lane + (u << 6);
    float p = (c < n) ? __expf(vals[u] - m) : 0.f;
    vals[u] = p;
    sum += p;
  }
#pragma unroll
  for (int off = 1; off < 64; off <<= 1) sum += __shfl_xor(sum, off);
  float rinv = 1.f / sum;
#pragma unroll
  for (int u = 0; u < 32; u++) {
    int c = lane + (u << 6);
    row[c] = f2bf(vals[u] * rinv);
  }
}

// ---------------------------------------------------------------------------
// Orchestration (all contractions are BT-GEMMs; see round-0 notes).
// ---------------------------------------------------------------------------
extern "C" void kernel_launch(void* const* d_in, const int* in_sizes, int n_in,
                              void* d_out, int out_size, void* d_ws, size_t ws_size,
                              hipStream_t stream) {
  const float* x  = (const float*)d_in[0];
  const float* fc = (const float*)d_in[1];
  const float* fs = (const float*)d_in[2];
  const float* wq = (const float*)d_in[4];
  const float* wk = (const float*)d_in[5];
  const float* wv = (const float*)d_in[6];
  const float* wo = (const float*)d_in[7];
  float* out = (float*)d_out;

  char* ws = (char*)d_ws;
  const size_t MB = 1024 * 1024;
  u16* XB  = (u16*)(ws + 0 * MB);
  u16* WQb = (u16*)(ws + 8 * MB);
  u16* WKb = (u16*)(ws + 16 * MB);
  u16* WVb = (u16*)(ws + 24 * MB);
  u16* WOb = (u16*)(ws + 32 * MB);
  u16* QB  = (u16*)(ws + 40 * MB);   // q[s][h*128+d]
  u16* KB  = (u16*)(ws + 48 * MB);   // k[s][h*128+d]
  u16* VT  = (u16*)(ws + 56 * MB);   // vT[h*128+d][s]
  u16* AT  = (u16*)(ws + 64 * MB);   // attn-out transposed [(h*128+d)][q]
  u16* SC  = (u16*)(ws + 72 * MB);   // scores, 8 MB per in-flight head

  int hpp = 16;
  while (hpp > 1 && 72 * MB + (size_t)hpp * 8 * MB > ws_size) hpp >>= 1;

  dim3 blk(256);
  cvt_bf16<<<4096, blk, 0, stream>>>((const floatx4*)x, (ushortx4*)XB);
  cvt_bf16_w4<<<dim3(4096, 4), blk, 0, stream>>>(
      (const floatx4*)wq, (const floatx4*)wk, (const floatx4*)wv, (const floatx4*)wo,
      (ushortx4*)WQb, (ushortx4*)WKb, (ushortx4*)WVb, (ushortx4*)WOb);

  // projections (M=N=K=2048)
  gemm_bt<<<dim3(16, 16, 1), blk, 0, stream>>>(XB,  WQb, QB, 2048, 2048, 2048,
                                               2048, 2048, 2048, 0, 0, 0, 1);
  gemm_bt<<<dim3(16, 16, 1), blk, 0, stream>>>(XB,  WKb, KB, 2048, 2048, 2048,
                                               2048, 2048, 2048, 0, 0, 0, 1);
  gemm_bt<<<dim3(16, 16, 1), blk, 0, stream>>>(WVb, XB,  VT, 2048, 2048, 2048,
                                               2048, 2048, 2048, 0, 0, 0, 1);

  rope_qk<<<dim3(8192, 2), blk, 0, stream>>>(QB, KB, fc, fs);

  for (int h0 = 0; h0 < 16; h0 += hpp) {
    // scores: S_h[q][s] = sum_d q[q][h*128+d] * k[s][h*128+d]   (K=128)
    gemm_bt<<<dim3(16, 16, hpp), blk, 0, stream>>>(QB + h0 * 128, KB + h0 * 128, SC,
        2048, 2048, 128, 2048, 2048, 2048, 128, 128, (long)2048 * 2048, 1);
    softmax_causal<<<hpp * 512, blk, 0, stream>>>(SC);
    // PV: AT_h[d][q] = sum_s vT_h[d][s] * P_h[q][s]   (M=128)
    gemm_bt<<<dim3(16, 1, hpp), blk, 0, stream>>>(VT + (size_t)h0 * 128 * 2048, SC,
        AT + (size_t)h0 * 128 * 2048,
        128, 2048, 2048, 2048, 2048, 2048,
        (long)128 * 2048, (long)2048 * 2048, (long)128 * 2048, 1);
  }

  // final: out[r][j] = sum_q AT[r][q] * wo[j][q]   (fp32 output)
  gemm_bt<<<dim3(16, 16, 1), blk, 0, stream>>>(AT, WOb, out, 2048, 2048, 2048,
                                               2048, 2048, 2048, 0, 0, 0, 0);
}

// Round 3
// 414.877 us; speedup vs baseline: 1.2557x; 1.1555x over previous
//
#include <hip/hip_runtime.h>

typedef unsigned short u16;
typedef unsigned int   u32;
typedef short  short8   __attribute__((ext_vector_type(8)));
typedef float  floatx4  __attribute__((ext_vector_type(4)));
typedef u16    ushortx2 __attribute__((ext_vector_type(2)));
typedef u16    ushortx4 __attribute__((ext_vector_type(4)));

__device__ __forceinline__ float bf2f(u16 u) {
  union { u32 i; float f; } v; v.i = ((u32)u) << 16; return v.f;
}
__device__ __forceinline__ u16 f2bf(float x) {
  union { float f; u32 i; } v; v.f = x;
  u32 r = v.i + 0x7FFFu + ((v.i >> 16) & 1u);   // round-to-nearest-even
  return (u16)(r >> 16);
}

// async global->LDS, 16B per lane; LDS dest = wave-uniform base + lane*16
#define GLOAD_LDS16(gptr, lptr)                                                   \
  __builtin_amdgcn_global_load_lds(                                               \
      (const __attribute__((address_space(1))) void*)(gptr),                      \
      (__attribute__((address_space(3))) void*)(lptr), 16, 0, 0)

// ---------------------------------------------------------------------------
// fp32 -> bf16 bulk convert (4 elems/thread)
// ---------------------------------------------------------------------------
__global__ __launch_bounds__(256) void cvt_bf16(const floatx4* __restrict__ in,
                                                ushortx4* __restrict__ out) {
  int i = blockIdx.x * 256 + threadIdx.x;
  floatx4 v = in[i];
  ushortx4 o;
  o.x = f2bf(v.x); o.y = f2bf(v.y); o.z = f2bf(v.z); o.w = f2bf(v.w);
  out[i] = o;
}

// 4 weight matrices in one launch (blockIdx.y selects); wq/wk/wv land
// contiguously so the QKV projection is one N=6144 GEMM.
__global__ __launch_bounds__(256) void cvt_bf16_w4(
    const floatx4* __restrict__ a, const floatx4* __restrict__ b,
    const floatx4* __restrict__ c, const floatx4* __restrict__ d,
    ushortx4* __restrict__ oa, ushortx4* __restrict__ ob,
    ushortx4* __restrict__ oc, ushortx4* __restrict__ od) {
  int i = blockIdx.x * 256 + threadIdx.x;
  const floatx4* in; ushortx4* out;
  switch (blockIdx.y) {
    case 0:  in = a; out = oa; break;
    case 1:  in = b; out = ob; break;
    case 2:  in = c; out = oc; break;
    default: in = d; out = od; break;
  }
  floatx4 v = in[i];
  ushortx4 o;
  o.x = f2bf(v.x); o.y = f2bf(v.y); o.z = f2bf(v.z); o.w = f2bf(v.w);
  out[i] = o;
}

// ---------------------------------------------------------------------------
// Batched BT-GEMM: C[m][n] = sum_k A[m][k] * B[n][k]   (A: MxK, B: NxK, bf16)
// 128x128 tile, BK=32, global_load_lds(16B) staging, XOR-swizzled LDS segs
// (2-way bank aliasing = free, m136).
// mode: 0 = plain; 1 = causal-scores (skip blocks with n0 > m0+127);
//       2 = causal-PV (K limited to n0+128).
// ---------------------------------------------------------------------------
__global__ __launch_bounds__(256) void gemm_bt(
    const u16* __restrict__ A, const u16* __restrict__ B, void* __restrict__ Cv,
    int M, int N, int K, int lda, int ldb, int ldc,
    long batchA, long batchB, long batchC, int outBF16, int mode) {
  const int m0 = blockIdx.y << 7;
  const int n0 = blockIdx.x << 7;
  if (mode == 1 && n0 > m0 + 127) return;          // fully-masked score tile
  int Keff = (mode == 2) ? (n0 + 128 < K ? n0 + 128 : K) : K;

  A += (long)blockIdx.z * batchA;
  B += (long)blockIdx.z * batchB;
  const long cbase = (long)blockIdx.z * batchC;

  __shared__ __align__(16) u16 As[128][32];
  __shared__ __align__(16) u16 Bs[128][32];

  const int t = threadIdx.x;
  const int lane = t & 63;
  const int wave = t >> 6;
  const int wm = (wave >> 1) << 6;   // wave row offset: 0 / 64
  const int wn = (wave & 1) << 6;    // wave col offset: 0 / 64
  const int quad = lane >> 4;        // k-quad: frag holds k = quad*8 + j
  const int mrow = lane & 15;        // m (A) / n (B) index within 16

  floatx4 acc[4][4] = {};

  // staging: wave w covers rows [w*32, w*32+32), two 16-row issues per matrix.
  const int srow = (wave << 5) + (lane >> 2);
  const int sseg = (((lane & 3) ^ ((lane >> 3) & 3)) << 3);   // u16 offset
  const u16* gA = A + (long)(m0 + srow) * lda + sseg;
  const u16* gB = B + (long)(n0 + srow) * ldb + sseg;
  u16* ldsA0 = &As[(wave << 5)][0];
  u16* ldsA1 = &As[(wave << 5) + 16][0];
  u16* ldsB0 = &Bs[(wave << 5)][0];
  u16* ldsB1 = &Bs[(wave << 5) + 16][0];

  // fragment read: quad seg of row lives at seg' = quad ^ ((mrow>>1)&3)
  const int qsw = ((quad ^ ((mrow >> 1) & 3)) << 3);          // u16 offset

  for (int k0 = 0; k0 < Keff; k0 += 32) {
    __syncthreads();
    GLOAD_LDS16(gA + k0,            ldsA0);
    GLOAD_LDS16(gA + k0 + 16 * lda, ldsA1);
    GLOAD_LDS16(gB + k0,            ldsB0);
    GLOAD_LDS16(gB + k0 + 16 * ldb, ldsB1);
    __syncthreads();

    short8 af[4], bfr[4];
#pragma unroll
    for (int i = 0; i < 4; i++)
      af[i] = *(const short8*)&As[wm + (i << 4) + mrow][qsw];
#pragma unroll
    for (int j = 0; j < 4; j++)
      bfr[j] = *(const short8*)&Bs[wn + (j << 4) + mrow][qsw];
#pragma unroll
    for (int i = 0; i < 4; i++)
#pragma unroll
      for (int j = 0; j < 4; j++)
        acc[i][j] = __builtin_amdgcn_mfma_f32_16x16x32_bf16(af[i], bfr[j], acc[i][j], 0, 0, 0);
  }

  // epilogue: C/D layout col = lane&15, row = quad*4 + reg  [measured m89/m91]
#pragma unroll
  for (int i = 0; i < 4; i++) {
    int row0 = m0 + wm + (i << 4) + (quad << 2);
#pragma unroll
    for (int j = 0; j < 4; j++) {
      int col = n0 + wn + (j << 4) + mrow;
#pragma unroll
      for (int r = 0; r < 4; r++) {
        long idx = cbase + (long)(row0 + r) * ldc + col;
        float val = acc[i][j][r];
        if (outBF16) ((u16*)Cv)[idx] = f2bf(val);
        else         ((float*)Cv)[idx] = val;
      }
    }
  }
}

// ---------------------------------------------------------------------------
// Transpose V (cols 4096..6143 of QKV, ld 6144) -> VT[d][s] (ld 2048). 64x64
// LDS tiles; both global accesses ushortx4-coalesced; LDS 2-way aliasing only.
// ---------------------------------------------------------------------------
__global__ __launch_bounds__(256) void transpose_v(const u16* __restrict__ src,
                                                   u16* __restrict__ dst) {
  __shared__ u16 tile[64][68];
  const int d0 = blockIdx.x << 6;   // V feature (dst row) base
  const int s0 = blockIdx.y << 6;   // seq (dst col) base
  const int tx = (threadIdx.x & 15) << 2;
  const int ty = threadIdx.x >> 4;
#pragma unroll
  for (int rr = 0; rr < 64; rr += 16) {
    ushortx4 v = *(const ushortx4*)(src + (size_t)(s0 + ty + rr) * 6144 + d0 + tx);
    *(ushortx4*)&tile[ty + rr][tx] = v;
  }
  __syncthreads();
#pragma unroll
  for (int rr = 0; rr < 64; rr += 16) {
    int r = ty + rr;
    ushortx4 o;
    o.x = tile[tx + 0][r]; o.y = tile[tx + 1][r];
    o.z = tile[tx + 2][r]; o.w = tile[tx + 3][r];
    *(ushortx4*)(dst + (size_t)(d0 + r) * 2048 + s0 + tx) = o;
  }
}

// ---------------------------------------------------------------------------
// RoPE in-place on QKV (row stride 6144). q additionally scaled by 1/sqrt(DH).
// ---------------------------------------------------------------------------
__global__ __launch_bounds__(256) void rope_qk(u16* __restrict__ qkv,
                                               const float* __restrict__ cs,
                                               const float* __restrict__ sn) {
  int idx = blockIdx.x * 256 + threadIdx.x;   // [0, 2048*16*64)
  int p = idx & 63;
  int h = (idx >> 6) & 15;
  int s = idx >> 10;
  float c  = cs[(s << 6) | p];
  float si = sn[(s << 6) | p];
  float scale = blockIdx.y ? 1.0f : 0.08838834764831845f;   // q: 1/sqrt(128)
  size_t off = (size_t)s * 6144 + (blockIdx.y ? 2048 : 0) + (h << 7) + (p << 1);
  ushortx2 eo = *(ushortx2*)(qkv + off);
  float e = bf2f(eo.x), o = bf2f(eo.y);
  ushortx2 r;
  r.x = f2bf((e * c - o * si) * scale);
  r.y = f2bf((e * si + o * c) * scale);
  *(ushortx2*)(qkv + off) = r;
}

// ---------------------------------------------------------------------------
// Causal softmax, in place. Wave per row. Writes only c < Klim = (q&~127)+128
// (PV never reads past Klim); masked cols inside Klim get exact 0.
// ---------------------------------------------------------------------------
__global__ __launch_bounds__(256) void softmax_causal(u16* __restrict__ sc) {
  int wid = (blockIdx.x << 2) | ((int)threadIdx.x >> 6);
  int lane = threadIdx.x & 63;
  int q  = wid & 2047;
  int hl = wid >> 11;
  u16* row = sc + ((size_t)hl * 2048 + q) * 2048;
  int n = q + 1;
  int Klim = (q & ~127) + 128;
  float vals[32];
  float m = -1e30f;
#pragma unroll
  for (int u = 0; u < 32; u++) {
    int c = lane + (u << 6);
    float v = (c < n) ? bf2f(row[c]) : -1e30f;
    vals[u] = v;
    m = fmaxf(m, v);
  }
#pragma unroll
  for (int off = 1; off < 64; off <<= 1) m = fmaxf(m, __shfl_xor(m, off));
  float sum = 0.f;
#pragma unroll
  for (int u = 0; u < 32; u++) {
    int c = lane + (u << 6);
    float p = (c < n) ? __expf(vals[u] - m) : 0.f;
    vals[u] = p;
    sum += p;
  }
#pragma unroll
  for (int off = 1; off < 64; off <<= 1) sum += __shfl_xor(sum, off);
  float rinv = 1.f / sum;
#pragma unroll
  for (int u = 0; u < 32; u++) {
    int c = lane + (u << 6);
    if (c < Klim) row[c] = f2bf(vals[u] * rinv);
  }
}

// out[i] = a[i] + b[i]  (split-K reduce, fp32x4)
__global__ __launch_bounds__(256) void reduce2(const floatx4* __restrict__ a,
                                               const floatx4* __restrict__ b,
                                               floatx4* __restrict__ o) {
  int i = blockIdx.x * 256 + threadIdx.x;
  o[i] = a[i] + b[i];
}

// ---------------------------------------------------------------------------
// Orchestration.
//   QKV[s][0:6144]   = BT(x, [wq;wk;wv])     (one 768-block GEMM)
//   VT[d][s]         = transpose(V part)
//   S_h[q][s]        = BT(q_h, k_h)          (triangular-skip)
//   AT_h[d][q]       = BT(vT_h, P_h)         (K capped at q-tile end)
//   out              = BT(AT, wo)            (split-K=2 + reduce)
// ---------------------------------------------------------------------------
extern "C" void kernel_launch(void* const* d_in, const int* in_sizes, int n_in,
                              void* d_out, int out_size, void* d_ws, size_t ws_size,
                              hipStream_t stream) {
  const float* x  = (const float*)d_in[0];
  const float* fc = (const float*)d_in[1];
  const float* fs = (const float*)d_in[2];
  const float* wq = (const float*)d_in[4];
  const float* wk = (const float*)d_in[5];
  const float* wv = (const float*)d_in[6];
  const float* wo = (const float*)d_in[7];
  float* out = (float*)d_out;

  char* ws = (char*)d_ws;
  const size_t MB = 1024 * 1024;
  u16*   XB   = (u16*)(ws + 0 * MB);     // bf16 x (8 MB)
  u16*   WQKV = (u16*)(ws + 8 * MB);     // [wq;wk;wv] 6144x2048 (24 MB)
  u16*   WOb  = (u16*)(ws + 32 * MB);    // wo (8 MB)
  u16*   QKV  = (u16*)(ws + 40 * MB);    // [s][6144] (24 MB)
  u16*   VT   = (u16*)(ws + 64 * MB);    // [d][s] (8 MB)
  u16*   AT   = (u16*)(ws + 72 * MB);    // [(h*128+d)][q] (8 MB)
  float* PART = (float*)(ws + 80 * MB);  // split-K partials (2 x 16 MB)

  int use_split = (ws_size >= 120 * MB);
  size_t sc_off = use_split ? 112 * MB : 80 * MB;
  u16* SC = (u16*)(ws + sc_off);

  int hpp = 16;
  while (hpp > 1 && sc_off + (size_t)hpp * 8 * MB > ws_size) hpp >>= 1;

  dim3 blk(256);
  cvt_bf16<<<4096, blk, 0, stream>>>((const floatx4*)x, (ushortx4*)XB);
  cvt_bf16_w4<<<dim3(4096, 4), blk, 0, stream>>>(
      (const floatx4*)wq, (const floatx4*)wk, (const floatx4*)wv, (const floatx4*)wo,
      (ushortx4*)WQKV, (ushortx4*)(WQKV + (size_t)2048 * 2048),
      (ushortx4*)(WQKV + (size_t)4096 * 2048), (ushortx4*)WOb);

  // fused QKV projection: M=2048, N=6144, K=2048 (768 blocks, 3/CU)
  gemm_bt<<<dim3(48, 16, 1), blk, 0, stream>>>(XB, WQKV, QKV, 2048, 6144, 2048,
                                               2048, 2048, 6144, 0, 0, 0, 1, 0);

  transpose_v<<<dim3(32, 32), blk, 0, stream>>>(QKV + 4096, VT);
  rope_qk<<<dim3(8192, 2), blk, 0, stream>>>(QKV, fc, fs);

  for (int h0 = 0; h0 < 16; h0 += hpp) {
    // scores: S_h[q][s] = sum_d q[q][.]*k[s][.]  (K=128, triangular skip)
    gemm_bt<<<dim3(16, 16, hpp), blk, 0, stream>>>(
        QKV + h0 * 128, QKV + 2048 + h0 * 128, SC,
        2048, 2048, 128, 6144, 6144, 2048, 128, 128, (long)2048 * 2048, 1, 1);
    softmax_causal<<<hpp * 512, blk, 0, stream>>>(SC);
    // PV: AT_h[d][q] = sum_s vT_h[d][s] * P_h[q][s]  (K capped at n0+128)
    gemm_bt<<<dim3(16, 1, hpp), blk, 0, stream>>>(
        VT + (size_t)h0 * 128 * 2048, SC, AT + (size_t)h0 * 128 * 2048,
        128, 2048, 2048, 2048, 2048, 2048,
        (long)128 * 2048, (long)2048 * 2048, (long)128 * 2048, 1, 2);
  }

  // final projection: out[r][j] = sum_q AT[r][q] * wo[j][q]
  if (use_split) {
    gemm_bt<<<dim3(16, 16, 2), blk, 0, stream>>>(AT, WOb, PART, 2048, 2048, 1024,
                                                 2048, 2048, 2048,
                                                 1024, 1024, (long)2048 * 2048, 0, 0);
    reduce2<<<4096, blk, 0, stream>>>((const floatx4*)PART,
                                      (const floatx4*)(PART + (size_t)2048 * 2048),
                                      (floatx4*)out);
  } else {
    gemm_bt<<<dim3(16, 16, 1), blk, 0, stream>>>(AT, WOb, out, 2048, 2048, 2048,
                                                 2048, 2048, 2048, 0, 0, 0, 0, 0);
  }
}

// Round 4
// 385.565 us; speedup vs baseline: 1.3511x; 1.0760x over previous
//
#include <hip/hip_runtime.h>

typedef unsigned short u16;
typedef unsigned int   u32;
typedef short  short8   __attribute__((ext_vector_type(8)));
typedef float  floatx4  __attribute__((ext_vector_type(4)));
typedef u16    ushortx2 __attribute__((ext_vector_type(2)));
typedef u16    ushortx4 __attribute__((ext_vector_type(4)));

__device__ __forceinline__ float bf2f(u16 u) {
  union { u32 i; float f; } v; v.i = ((u32)u) << 16; return v.f;
}
__device__ __forceinline__ u16 f2bf(float x) {
  union { float f; u32 i; } v; v.f = x;
  u32 r = v.i + 0x7FFFu + ((v.i >> 16) & 1u);   // round-to-nearest-even
  return (u16)(r >> 16);
}

// async global->LDS, 16B per lane; LDS dest = wave-uniform base + lane*16
#define GLOAD_LDS16(gptr, lptr)                                                   \
  __builtin_amdgcn_global_load_lds(                                               \
      (const __attribute__((address_space(1))) void*)(gptr),                      \
      (__attribute__((address_space(3))) void*)(lptr), 16, 0, 0)

// ---------------------------------------------------------------------------
// fp32 -> bf16 bulk convert (4 elems/thread)
// ---------------------------------------------------------------------------
__global__ __launch_bounds__(256) void cvt_bf16(const floatx4* __restrict__ in,
                                                ushortx4* __restrict__ out) {
  int i = blockIdx.x * 256 + threadIdx.x;
  floatx4 v = in[i];
  ushortx4 o;
  o.x = f2bf(v.x); o.y = f2bf(v.y); o.z = f2bf(v.z); o.w = f2bf(v.w);
  out[i] = o;
}

// 4 weight matrices in one launch; wq/wk/wv land contiguously for fused QKV.
__global__ __launch_bounds__(256) void cvt_bf16_w4(
    const floatx4* __restrict__ a, const floatx4* __restrict__ b,
    const floatx4* __restrict__ c, const floatx4* __restrict__ d,
    ushortx4* __restrict__ oa, ushortx4* __restrict__ ob,
    ushortx4* __restrict__ oc, ushortx4* __restrict__ od) {
  int i = blockIdx.x * 256 + threadIdx.x;
  const floatx4* in; ushortx4* out;
  switch (blockIdx.y) {
    case 0:  in = a; out = oa; break;
    case 1:  in = b; out = ob; break;
    case 2:  in = c; out = oc; break;
    default: in = d; out = od; break;
  }
  floatx4 v = in[i];
  ushortx4 o;
  o.x = f2bf(v.x); o.y = f2bf(v.y); o.z = f2bf(v.z); o.w = f2bf(v.w);
  out[i] = o;
}

// ---------------------------------------------------------------------------
// BT-GEMM: C[m][n] = sum_k A[m][k]*B[n][k]. 128x128 tile, BK=32,
// global_load_lds(16B), XOR-swizzled LDS (0 bank conflicts, verified R2/R3).
// ---------------------------------------------------------------------------
__global__ __launch_bounds__(256) void gemm_bt(
    const u16* __restrict__ A, const u16* __restrict__ B, void* __restrict__ Cv,
    int M, int N, int K, int lda, int ldb, int ldc,
    long batchA, long batchB, long batchC, int outBF16) {
  const int m0 = blockIdx.y << 7;
  const int n0 = blockIdx.x << 7;

  A += (long)blockIdx.z * batchA;
  B += (long)blockIdx.z * batchB;
  const long cbase = (long)blockIdx.z * batchC;

  __shared__ __align__(16) u16 As[128][32];
  __shared__ __align__(16) u16 Bs[128][32];

  const int t = threadIdx.x;
  const int lane = t & 63;
  const int wave = t >> 6;
  const int wm = (wave >> 1) << 6;
  const int wn = (wave & 1) << 6;
  const int quad = lane >> 4;
  const int mrow = lane & 15;

  floatx4 acc[4][4] = {};

  const int srow = (wave << 5) + (lane >> 2);
  const int sseg = (((lane & 3) ^ ((lane >> 3) & 3)) << 3);
  const u16* gA = A + (long)(m0 + srow) * lda + sseg;
  const u16* gB = B + (long)(n0 + srow) * ldb + sseg;
  u16* ldsA0 = &As[(wave << 5)][0];
  u16* ldsA1 = &As[(wave << 5) + 16][0];
  u16* ldsB0 = &Bs[(wave << 5)][0];
  u16* ldsB1 = &Bs[(wave << 5) + 16][0];

  const int qsw = ((quad ^ ((mrow >> 1) & 3)) << 3);

  for (int k0 = 0; k0 < K; k0 += 32) {
    __syncthreads();
    GLOAD_LDS16(gA + k0,            ldsA0);
    GLOAD_LDS16(gA + k0 + 16 * lda, ldsA1);
    GLOAD_LDS16(gB + k0,            ldsB0);
    GLOAD_LDS16(gB + k0 + 16 * ldb, ldsB1);
    __syncthreads();

    short8 af[4], bfr[4];
#pragma unroll
    for (int i = 0; i < 4; i++)
      af[i] = *(const short8*)&As[wm + (i << 4) + mrow][qsw];
#pragma unroll
    for (int j = 0; j < 4; j++)
      bfr[j] = *(const short8*)&Bs[wn + (j << 4) + mrow][qsw];
#pragma unroll
    for (int i = 0; i < 4; i++)
#pragma unroll
      for (int j = 0; j < 4; j++)
        acc[i][j] = __builtin_amdgcn_mfma_f32_16x16x32_bf16(af[i], bfr[j], acc[i][j], 0, 0, 0);
  }

  // C/D layout: col = lane&15, row = quad*4 + reg  [measured m89/m91]
#pragma unroll
  for (int i = 0; i < 4; i++) {
    int row0 = m0 + wm + (i << 4) + (quad << 2);
#pragma unroll
    for (int j = 0; j < 4; j++) {
      int col = n0 + wn + (j << 4) + mrow;
#pragma unroll
      for (int r = 0; r < 4; r++) {
        long idx = cbase + (long)(row0 + r) * ldc + col;
        float val = acc[i][j][r];
        if (outBF16) ((u16*)Cv)[idx] = f2bf(val);
        else         ((float*)Cv)[idx] = val;
      }
    }
  }
}

// ---------------------------------------------------------------------------
// Transpose V (cols 4096..6143 of QKV, ld 6144) -> VT[d][s] (ld 2048).
// ---------------------------------------------------------------------------
__global__ __launch_bounds__(256) void transpose_v(const u16* __restrict__ src,
                                                   u16* __restrict__ dst) {
  __shared__ u16 tile[64][68];
  const int d0 = blockIdx.x << 6;
  const int s0 = blockIdx.y << 6;
  const int tx = (threadIdx.x & 15) << 2;
  const int ty = threadIdx.x >> 4;
#pragma unroll
  for (int rr = 0; rr < 64; rr += 16) {
    ushortx4 v = *(const ushortx4*)(src + (size_t)(s0 + ty + rr) * 6144 + d0 + tx);
    *(ushortx4*)&tile[ty + rr][tx] = v;
  }
  __syncthreads();
#pragma unroll
  for (int rr = 0; rr < 64; rr += 16) {
    int r = ty + rr;
    ushortx4 o;
    o.x = tile[tx + 0][r]; o.y = tile[tx + 1][r];
    o.z = tile[tx + 2][r]; o.w = tile[tx + 3][r];
    *(ushortx4*)(dst + (size_t)(d0 + r) * 2048 + s0 + tx) = o;
  }
}

// ---------------------------------------------------------------------------
// RoPE in-place on QKV (row stride 6144). q pre-scaled by 1/sqrt(DH).
// ---------------------------------------------------------------------------
__global__ __launch_bounds__(256) void rope_qk(u16* __restrict__ qkv,
                                               const float* __restrict__ cs,
                                               const float* __restrict__ sn) {
  int idx = blockIdx.x * 256 + threadIdx.x;
  int p = idx & 63;
  int h = (idx >> 6) & 15;
  int s = idx >> 10;
  float c  = cs[(s << 6) | p];
  float si = sn[(s << 6) | p];
  float scale = blockIdx.y ? 1.0f : 0.08838834764831845f;
  size_t off = (size_t)s * 6144 + (blockIdx.y ? 2048 : 0) + (h << 7) + (p << 1);
  ushortx2 eo = *(ushortx2*)(qkv + off);
  float e = bf2f(eo.x), o = bf2f(eo.y);
  ushortx2 r;
  r.x = f2bf((e * c - o * si) * scale);
  r.y = f2bf((e * si + o * c) * scale);
  *(ushortx2*)(qkv + off) = r;
}

// ---------------------------------------------------------------------------
// Fused flash attention, one block per (q-tile, head). 4 waves, 128x128 tiles.
// Per kt<=qt: stage K/VT tiles (global_load_lds, swizzled), S=QK^T (fp32 accs),
// online softmax (shuffle + LDS cross-wave), P->LDS (B-frag layout),
// O^T[d][q] += VT·P^T with alpha rescale. Output AT[(h*128+d)][q] bf16.
// ---------------------------------------------------------------------------
__global__ __launch_bounds__(256) void flash_attn(
    const u16* __restrict__ QKVp, const u16* __restrict__ VTp,
    u16* __restrict__ ATp) {
  const int qt = blockIdx.x;
  const int h  = blockIdx.y;

  __shared__ __align__(16) u16 Qs[128][128];
  __shared__ __align__(16) u16 Ks[128][128];
  __shared__ __align__(16) u16 Vs[128][128];
  __shared__ __align__(16) u16 Ps[128][136];
  __shared__ float redm[128][2];
  __shared__ float redl[128][2];
  __shared__ float mstate[128];
  __shared__ float lstate[128];
  __shared__ float abuf[128];

  const int t = threadIdx.x;
  const int lane = t & 63;
  const int wave = t >> 6;
  const int quad = lane >> 4;
  const int mrow = lane & 15;
  const int sw   = mrow & 7;           // frag-read swizzle term (row&7)
  const int wm = (wave >> 1) << 6;
  const int wn = (wave & 1) << 6;
  const int half = wave & 1;

  // staging mapping: issue = 4 rows x 16 segs; lane's LDS slot (row r4, seg)
  // must receive global col-seg c = seg ^ ((r0 + r4) & 7)
  const int r4  = lane >> 4;
  const int seg = lane & 15;
  const int c0 = ((seg ^ r4) << 3);        // r0 % 8 == 0
  const int c4 = ((seg ^ (r4 + 4)) << 3);  // r0 % 8 == 4

  const u16* qbase = QKVp + (size_t)(qt << 7) * 6144 + (h << 7);
  const u16* kbase = QKVp + 2048 + (h << 7);
  const u16* vbase = VTp + (size_t)(h << 7) * 2048;

  {
    int r0 = wave << 5;
#pragma unroll
    for (int ii = 0; ii < 8; ii++) {
      int rr = r0 + (ii << 2);
      GLOAD_LDS16(qbase + (size_t)(rr + r4) * 6144 + ((ii & 1) ? c4 : c0), &Qs[rr][0]);
    }
  }
  if (t < 128) { mstate[t] = -3e38f; lstate[t] = 0.f; }

  floatx4 Oa[4][4] = {};

  for (int kt = 0; kt <= qt; kt++) {
    __syncthreads();                     // B1: prev Ks/Vs/Ps fully consumed
    {
      int r0 = wave << 5;
#pragma unroll
      for (int ii = 0; ii < 8; ii++) {
        int rr = r0 + (ii << 2);
        GLOAD_LDS16(kbase + (size_t)((kt << 7) + rr + r4) * 6144 + ((ii & 1) ? c4 : c0),
                    &Ks[rr][0]);
      }
    }
    // read running state (written prev iter after B3/B4; B1 separates)
    float mold[4][4], lold[4][4];
#pragma unroll
    for (int i = 0; i < 4; i++)
#pragma unroll
      for (int r = 0; r < 4; r++)
        mold[i][r] = mstate[wm + (i << 4) + (quad << 2) + r];
    if (half == 0 && mrow == 0)
#pragma unroll
      for (int i = 0; i < 4; i++)
#pragma unroll
        for (int r = 0; r < 4; r++)
          lold[i][r] = lstate[wm + (i << 4) + (quad << 2) + r];

    __syncthreads();                     // B2: Ks ready (Qs too on iter 0)
    {
      int r0 = wave << 5;                // V staging overlaps S compute
#pragma unroll
      for (int ii = 0; ii < 8; ii++) {
        int rr = r0 + (ii << 2);
        GLOAD_LDS16(vbase + (size_t)(rr + r4) * 2048 + (kt << 7) + ((ii & 1) ? c4 : c0),
                    &Vs[rr][0]);
      }
    }
    // S = Q·K^T (K=128)
    floatx4 sa[4][4] = {};
#pragma unroll
    for (int kk = 0; kk < 4; kk++) {
      short8 aq[4], bk[4];
#pragma unroll
      for (int i = 0; i < 4; i++)
        aq[i] = *(const short8*)&Qs[wm + (i << 4) + mrow][(((kk << 2) | quad) ^ sw) << 3];
#pragma unroll
      for (int j = 0; j < 4; j++)
        bk[j] = *(const short8*)&Ks[wn + (j << 4) + mrow][(((kk << 2) | quad) ^ sw) << 3];
#pragma unroll
      for (int i = 0; i < 4; i++)
#pragma unroll
        for (int j = 0; j < 4; j++)
          sa[i][j] = __builtin_amdgcn_mfma_f32_16x16x32_bf16(aq[i], bk[j], sa[i][j], 0, 0, 0);
    }
    if (kt == qt) {                      // causal mask on diagonal tile
#pragma unroll
      for (int i = 0; i < 4; i++)
#pragma unroll
        for (int j = 0; j < 4; j++)
#pragma unroll
          for (int r = 0; r < 4; r++) {
            int ql = wm + (i << 4) + (quad << 2) + r;
            int sl = wn + (j << 4) + mrow;
            if (sl > ql) sa[i][j][r] = -1e30f;
          }
    }
    // row-max: per-lane over j, butterfly over the 16 mrow lanes
    float rv[4][4];
#pragma unroll
    for (int i = 0; i < 4; i++)
#pragma unroll
      for (int r = 0; r < 4; r++) {
        float v = fmaxf(fmaxf(sa[i][0][r], sa[i][1][r]), fmaxf(sa[i][2][r], sa[i][3][r]));
#pragma unroll
        for (int off = 1; off <= 8; off <<= 1) v = fmaxf(v, __shfl_xor(v, off));
        rv[i][r] = v;
      }
    if (mrow == 0)
#pragma unroll
      for (int i = 0; i < 4; i++)
#pragma unroll
        for (int r = 0; r < 4; r++)
          redm[wm + (i << 4) + (quad << 2) + r][half] = rv[i][r];
    __syncthreads();                     // B3: redm ready (Vs also drained)
    float mnew[4][4];
#pragma unroll
    for (int i = 0; i < 4; i++)
#pragma unroll
      for (int r = 0; r < 4; r++) {
        int row = wm + (i << 4) + (quad << 2) + r;
        mnew[i][r] = fmaxf(mold[i][r], fmaxf(redm[row][0], redm[row][1]));
      }
#pragma unroll
    for (int i = 0; i < 4; i++)
#pragma unroll
      for (int j = 0; j < 4; j++)
#pragma unroll
        for (int r = 0; r < 4; r++)
          sa[i][j][r] = __expf(sa[i][j][r] - mnew[i][r]);
#pragma unroll
    for (int i = 0; i < 4; i++)
#pragma unroll
      for (int r = 0; r < 4; r++) {
        float s = sa[i][0][r] + sa[i][1][r] + sa[i][2][r] + sa[i][3][r];
#pragma unroll
        for (int off = 1; off <= 8; off <<= 1) s += __shfl_xor(s, off);
        rv[i][r] = s;
      }
    if (mrow == 0) {
#pragma unroll
      for (int i = 0; i < 4; i++)
#pragma unroll
        for (int r = 0; r < 4; r++)
          redl[wm + (i << 4) + (quad << 2) + r][half] = rv[i][r];
      if (half == 0)
#pragma unroll
        for (int i = 0; i < 4; i++)
#pragma unroll
          for (int r = 0; r < 4; r++) {
            int row = wm + (i << 4) + (quad << 2) + r;
            abuf[row]   = __expf(mold[i][r] - mnew[i][r]);
            mstate[row] = mnew[i][r];
          }
    }
    // P tile -> LDS in B-fragment layout [q][s] (pad 136: <=2-way banks)
#pragma unroll
    for (int i = 0; i < 4; i++)
#pragma unroll
      for (int j = 0; j < 4; j++)
#pragma unroll
        for (int r = 0; r < 4; r++)
          Ps[wm + (i << 4) + (quad << 2) + r][wn + (j << 4) + mrow] = f2bf(sa[i][j][r]);
    __syncthreads();                     // B4: Ps, Vs, abuf, redl ready
    float aj[4];
#pragma unroll
    for (int j = 0; j < 4; j++) aj[j] = abuf[wn + (j << 4) + mrow];
#pragma unroll
    for (int i = 0; i < 4; i++)
#pragma unroll
      for (int j = 0; j < 4; j++) Oa[i][j] *= aj[j];
    // O^T[d][q] += VT·P^T   (A = Vs rows d, B = Ps rows q, k = s)
#pragma unroll
    for (int kk = 0; kk < 4; kk++) {
      short8 av[4], bp[4];
#pragma unroll
      for (int i = 0; i < 4; i++)
        av[i] = *(const short8*)&Vs[wm + (i << 4) + mrow][(((kk << 2) | quad) ^ sw) << 3];
#pragma unroll
      for (int j = 0; j < 4; j++)
        bp[j] = *(const short8*)&Ps[wn + (j << 4) + mrow][(kk << 5) | (quad << 3)];
#pragma unroll
      for (int i = 0; i < 4; i++)
#pragma unroll
        for (int j = 0; j < 4; j++)
          Oa[i][j] = __builtin_amdgcn_mfma_f32_16x16x32_bf16(av[i], bp[j], Oa[i][j], 0, 0, 0);
    }
    if (half == 0 && mrow == 0)
#pragma unroll
      for (int i = 0; i < 4; i++)
#pragma unroll
        for (int r = 0; r < 4; r++) {
          int row = wm + (i << 4) + (quad << 2) + r;
          float al = __expf(mold[i][r] - mnew[i][r]);
          lstate[row] = al * lold[i][r] + redl[row][0] + redl[row][1];
        }
  }
  __syncthreads();
  float linv[4];
#pragma unroll
  for (int j = 0; j < 4; j++) linv[j] = 1.f / lstate[wn + (j << 4) + mrow];
#pragma unroll
  for (int i = 0; i < 4; i++) {
    int drow = (h << 7) + wm + (i << 4) + (quad << 2);
#pragma unroll
    for (int j = 0; j < 4; j++) {
      int col = (qt << 7) + wn + (j << 4) + mrow;
#pragma unroll
      for (int r = 0; r < 4; r++)
        ATp[(size_t)(drow + r) * 2048 + col] = f2bf(Oa[i][j][r] * linv[j]);
    }
  }
}

// out[i] = a[i] + b[i]  (split-K reduce, fp32x4)
__global__ __launch_bounds__(256) void reduce2(const floatx4* __restrict__ a,
                                               const floatx4* __restrict__ b,
                                               floatx4* __restrict__ o) {
  int i = blockIdx.x * 256 + threadIdx.x;
  o[i] = a[i] + b[i];
}

// ---------------------------------------------------------------------------
// Orchestration:
//   QKV = BT(x, [wq;wk;wv]); VT = transpose(V); rope(Q,K);
//   AT  = flash_attn(Q, K, VT);  out = BT(AT, wo) (split-K=2).
// ---------------------------------------------------------------------------
extern "C" void kernel_launch(void* const* d_in, const int* in_sizes, int n_in,
                              void* d_out, int out_size, void* d_ws, size_t ws_size,
                              hipStream_t stream) {
  const float* x  = (const float*)d_in[0];
  const float* fc = (const float*)d_in[1];
  const float* fs = (const float*)d_in[2];
  const float* wq = (const float*)d_in[4];
  const float* wk = (const float*)d_in[5];
  const float* wv = (const float*)d_in[6];
  const float* wo = (const float*)d_in[7];
  float* out = (float*)d_out;

  char* ws = (char*)d_ws;
  const size_t MB = 1024 * 1024;
  u16*   XB   = (u16*)(ws + 0 * MB);
  u16*   WQKV = (u16*)(ws + 8 * MB);     // [wq;wk;wv] 6144x2048
  u16*   WOb  = (u16*)(ws + 32 * MB);
  u16*   QKV  = (u16*)(ws + 40 * MB);    // [s][6144]
  u16*   VT   = (u16*)(ws + 64 * MB);    // [d][s]
  u16*   AT   = (u16*)(ws + 72 * MB);    // [(h*128+d)][q]
  float* PART = (float*)(ws + 80 * MB);  // split-K partials (2 x 16 MB)

  int use_split = (ws_size >= 113 * MB);

  dim3 blk(256);
  cvt_bf16<<<4096, blk, 0, stream>>>((const floatx4*)x, (ushortx4*)XB);
  cvt_bf16_w4<<<dim3(4096, 4), blk, 0, stream>>>(
      (const floatx4*)wq, (const floatx4*)wk, (const floatx4*)wv, (const floatx4*)wo,
      (ushortx4*)WQKV, (ushortx4*)(WQKV + (size_t)2048 * 2048),
      (ushortx4*)(WQKV + (size_t)4096 * 2048), (ushortx4*)WOb);

  // fused QKV projection: M=2048, N=6144, K=2048
  gemm_bt<<<dim3(48, 16, 1), blk, 0, stream>>>(XB, WQKV, QKV, 2048, 6144, 2048,
                                               2048, 2048, 6144, 0, 0, 0, 1);

  transpose_v<<<dim3(32, 32), blk, 0, stream>>>(QKV + 4096, VT);
  rope_qk<<<dim3(8192, 2), blk, 0, stream>>>(QKV, fc, fs);

  flash_attn<<<dim3(16, 16), blk, 0, stream>>>(QKV, VT, AT);

  // final projection: out[r][j] = sum_q AT[r][q] * wo[j][q]
  if (use_split) {
    gemm_bt<<<dim3(16, 16, 2), blk, 0, stream>>>(AT, WOb, PART, 2048, 2048, 1024,
                                                 2048, 2048, 2048,
                                                 1024, 1024, (long)2048 * 2048, 0);
    reduce2<<<4096, blk, 0, stream>>>((const floatx4*)PART,
                                      (const floatx4*)(PART + (size_t)2048 * 2048),
                                      (floatx4*)out);
  } else {
    gemm_bt<<<dim3(16, 16, 1), blk, 0, stream>>>(AT, WOb, out, 2048, 2048, 2048,
                                                 2048, 2048, 2048, 0, 0, 0, 0);
  }
}